// Round 1
// baseline (3520.111 us; speedup 1.0000x reference)
//
#include <hip/hip_runtime.h>

// Problem: B=8, T=2048, D=1024, E(D_OUT)=1024
//   y = x@W + b                         (bf16, stored in d_out[0:32MiB])
//   S[b,t,s] = y_t . y_s / 32, mask s<=t
//   attn = softmax over t (columns):  per (b,s): m_s = max_{t>=s}, Z_s = sumexp
//   out[b,t,:] = sum_{s<=t} exp(S[t,s]-m_s)/Z_s * x[b,s,:]
//
// Memory plan:
//   d_ws : S/P bf16 [B,T,T] = 64 MiB  (requires ws_size >= 64 MiB)
//   d_out: y bf16 [B*T*E] = 32 MiB  | m fp32 [B*T] | r fp32 [B*T]   (all dead
//          before k4 overwrites d_out with the final fp32 output)
//
// Precision note: stats (m,Z) are computed from bf16-ROUNDED scores so the
// stored-S numerator is exactly consistent with the max -> diag attn == 1.

#define B_ 8
#define T_ 2048
#define D_ 1024
#define E_ 1024

typedef unsigned short u16;

__device__ __forceinline__ float b2f(u16 u) {
    unsigned v = ((unsigned)u) << 16;
    float f; __builtin_memcpy(&f, &v, 4); return f;
}
__device__ __forceinline__ u16 f2b(float f) {
    unsigned v; __builtin_memcpy(&v, &f, 4);
    v = (v + 0x7FFFu + ((v >> 16) & 1u)) >> 16;   // RNE
    return (u16)v;
}

// ---------------- K1: y = bf16(x @ W + b) ----------------
// M=B*T=16384, N=E=1024, K=D=1024. Tile 64x64x16, 256 thr, 4x4/thread.
__global__ __launch_bounds__(256) void k1_proj(const float* __restrict__ x,
                                               const float* __restrict__ W,
                                               const float* __restrict__ bias,
                                               u16* __restrict__ y)
{
    __shared__ float As[64][17];
    __shared__ float Bs[16][64];
    const int tid = threadIdx.x;
    const int tx = tid & 15, ty = tid >> 4;
    const int m0 = blockIdx.y * 64;
    const int n0 = blockIdx.x * 64;
    const int l = tid * 4;
    const int alr = l >> 4, alc = l & 15;   // A: 64 rows x 16 k
    const int blr = l >> 6, blc = l & 63;   // B: 16 k x 64 cols
    float acc[4][4] = {};
    for (int k0 = 0; k0 < D_; k0 += 16) {
        float4 av = *(const float4*)(x + (size_t)(m0 + alr) * D_ + k0 + alc);
        float4 bv = *(const float4*)(W + (size_t)(k0 + blr) * E_ + n0 + blc);
        __syncthreads();
        As[alr][alc] = av.x; As[alr][alc+1] = av.y; As[alr][alc+2] = av.z; As[alr][alc+3] = av.w;
        *(float4*)&Bs[blr][blc] = bv;
        __syncthreads();
#pragma unroll
        for (int k = 0; k < 16; k++) {
            float a[4], bb[4];
#pragma unroll
            for (int i = 0; i < 4; i++) a[i] = As[ty*4 + i][k];
#pragma unroll
            for (int j = 0; j < 4; j++) bb[j] = Bs[k][tx*4 + j];
#pragma unroll
            for (int i = 0; i < 4; i++)
#pragma unroll
                for (int j = 0; j < 4; j++) acc[i][j] += a[i] * bb[j];
        }
    }
#pragma unroll
    for (int i = 0; i < 4; i++) {
        const int gm = m0 + ty*4 + i;
        ushort4 pk;
        pk.x = f2b(acc[i][0] + bias[n0 + tx*4 + 0]);
        pk.y = f2b(acc[i][1] + bias[n0 + tx*4 + 1]);
        pk.z = f2b(acc[i][2] + bias[n0 + tx*4 + 2]);
        pk.w = f2b(acc[i][3] + bias[n0 + tx*4 + 3]);
        *(ushort4*)(y + (size_t)gm * E_ + n0 + tx*4) = pk;
    }
}

// ---------------- K2: column stats + store raw S (bf16) ----------------
// Workgroup owns 64 columns s in [s0,s0+64) of batch b; loops t-tiles from the
// diagonal down. Computes S tile = y_t . y_s / 32 (fp32), rounds to bf16,
// stores, and keeps running per-column (m, z) with online rescale.
__global__ __launch_bounds__(256) void k2_stats(const u16* __restrict__ y,
                                                u16* __restrict__ S,
                                                float* __restrict__ mout,
                                                float* __restrict__ rout)
{
    __shared__ float As[64][17];   // t rows x k
    __shared__ float Bs[64][17];   // s rows x k
    __shared__ float red[16][64];
    __shared__ float mcol[64];
    __shared__ float mrun[64];
    __shared__ float zrun[64];
    const int tid = threadIdx.x;
    const int tx = tid & 15, ty = tid >> 4;
    const int b = blockIdx.y;
    const int s0 = blockIdx.x * 64;
    const u16* yb = y + (size_t)b * T_ * E_;
    if (tid < 64) { mrun[tid] = -3e38f; zrun[tid] = 0.f; }
    __syncthreads();
    const int l = tid * 4;
    const int lr = l >> 4, lc = l & 15;
    for (int t0 = s0; t0 < T_; t0 += 64) {
        float acc[4][4] = {};
        for (int k0 = 0; k0 < E_; k0 += 16) {
            ushort4 av = *(const ushort4*)(yb + (size_t)(t0 + lr) * E_ + k0 + lc);
            ushort4 bv = *(const ushort4*)(yb + (size_t)(s0 + lr) * E_ + k0 + lc);
            __syncthreads();
            As[lr][lc] = b2f(av.x); As[lr][lc+1] = b2f(av.y); As[lr][lc+2] = b2f(av.z); As[lr][lc+3] = b2f(av.w);
            Bs[lr][lc] = b2f(bv.x); Bs[lr][lc+1] = b2f(bv.y); Bs[lr][lc+2] = b2f(bv.z); Bs[lr][lc+3] = b2f(bv.w);
            __syncthreads();
#pragma unroll
            for (int k = 0; k < 16; k++) {
                float a[4], bb[4];
#pragma unroll
                for (int i = 0; i < 4; i++) a[i] = As[ty*4 + i][k];
#pragma unroll
                for (int j = 0; j < 4; j++) bb[j] = Bs[tx*4 + j][k];
#pragma unroll
                for (int i = 0; i < 4; i++)
#pragma unroll
                    for (int j = 0; j < 4; j++) acc[i][j] += a[i] * bb[j];
            }
        }
        // scale, bf16-round (consistency with stored S!), mask
        float vals[4][4];
#pragma unroll
        for (int i = 0; i < 4; i++)
#pragma unroll
            for (int j = 0; j < 4; j++) {
                const int tt = t0 + ty*4 + i, ss = s0 + tx*4 + j;
                float v = b2f(f2b(acc[i][j] * 0.03125f));
                if (tt < ss) v = -3e38f;
                vals[i][j] = v;
            }
        // store raw S tile
#pragma unroll
        for (int i = 0; i < 4; i++) {
            ushort4 pk;
            pk.x = f2b(vals[i][0]); pk.y = f2b(vals[i][1]);
            pk.z = f2b(vals[i][2]); pk.w = f2b(vals[i][3]);
            *(ushort4*)(S + ((size_t)(b * T_ + t0 + ty*4 + i)) * T_ + s0 + tx*4) = pk;
        }
        // per-column max across the 64 t rows of this tile
        float cm[4];
#pragma unroll
        for (int j = 0; j < 4; j++)
            cm[j] = fmaxf(fmaxf(vals[0][j], vals[1][j]), fmaxf(vals[2][j], vals[3][j]));
        __syncthreads();
#pragma unroll
        for (int j = 0; j < 4; j++) red[ty][tx*4 + j] = cm[j];
        __syncthreads();
        if (tid < 64) {
            float m = red[0][tid];
#pragma unroll
            for (int rr = 1; rr < 16; rr++) m = fmaxf(m, red[rr][tid]);
            m = fmaxf(m, mrun[tid]);
            mcol[tid] = m;
        }
        __syncthreads();
        float ps[4];
#pragma unroll
        for (int j = 0; j < 4; j++) {
            const float mm = mcol[tx*4 + j];
            float ss_ = 0.f;
#pragma unroll
            for (int i = 0; i < 4; i++) ss_ += __expf(vals[i][j] - mm);
            ps[j] = ss_;
        }
#pragma unroll
        for (int j = 0; j < 4; j++) red[ty][tx*4 + j] = ps[j];
        __syncthreads();
        if (tid < 64) {
            float zs = 0.f;
#pragma unroll
            for (int rr = 0; rr < 16; rr++) zs += red[rr][tid];
            const float mo = mrun[tid], mn = mcol[tid];
            zrun[tid] = zrun[tid] * __expf(mo - mn) + zs;
            mrun[tid] = mn;
        }
        __syncthreads();
    }
    if (tid < 64) {
        mout[(size_t)b * T_ + s0 + tid] = mrun[tid];
        rout[(size_t)b * T_ + s0 + tid] = 1.0f / zrun[tid];
    }
}

// ---------------- K3: P = exp(S - m_s) * r_s  (in place, bf16) ----------------
// One block per (b,t) row; 256 threads x 8 elems = 2048 = T.
__global__ __launch_bounds__(256) void k3_pnorm(u16* __restrict__ S,
                                                const float* __restrict__ m,
                                                const float* __restrict__ r)
{
    const int row = blockIdx.x;          // b*T + t
    const int b = row >> 11;
    const int t = row & (T_ - 1);
    const int s0 = threadIdx.x * 8;
    u16* Sp = S + (size_t)row * T_ + s0;
    const float* mb = m + (size_t)b * T_;
    const float* rb = r + (size_t)b * T_;
    ushort4 v0 = *(ushort4*)Sp;
    ushort4 v1 = *(ushort4*)(Sp + 4);
    u16 vv[8] = { v0.x, v0.y, v0.z, v0.w, v1.x, v1.y, v1.z, v1.w };
    u16 ov[8];
#pragma unroll
    for (int i = 0; i < 8; i++) {
        const int s = s0 + i;
        float p = 0.f;
        if (s <= t) p = __expf(b2f(vv[i]) - mb[s]) * rb[s];
        ov[i] = f2b(p);
    }
    *(ushort4*)Sp       = make_ushort4(ov[0], ov[1], ov[2], ov[3]);
    *(ushort4*)(Sp + 4) = make_ushort4(ov[4], ov[5], ov[6], ov[7]);
}

// ---------------- K4: out = P @ x  (per batch, causal K-range) ----------------
__global__ __launch_bounds__(256) void k4_out(const u16* __restrict__ P,
                                              const float* __restrict__ x,
                                              float* __restrict__ out)
{
    __shared__ float As[64][17];   // P rows t x k(s)
    __shared__ float Bs[16][64];   // x k(s) x d
    const int tid = threadIdx.x;
    const int tx = tid & 15, ty = tid >> 4;
    const int b = blockIdx.z;
    const int t0 = blockIdx.y * 64;
    const int d0 = blockIdx.x * 64;
    const u16* Pb = P + (size_t)b * T_ * T_;
    const float* xb = x + (size_t)b * T_ * D_;
    const int l = tid * 4;
    const int alr = l >> 4, alc = l & 15;
    const int blr = l >> 6, blc = l & 63;
    float acc[4][4] = {};
    const int kend = t0 + 64;   // P[t,s]=0 for s>t
    for (int k0 = 0; k0 < kend; k0 += 16) {
        ushort4 av = *(const ushort4*)(Pb + (size_t)(t0 + alr) * T_ + k0 + alc);
        float4 bv = *(const float4*)(xb + (size_t)(k0 + blr) * D_ + d0 + blc);
        __syncthreads();
        As[alr][alc] = b2f(av.x); As[alr][alc+1] = b2f(av.y); As[alr][alc+2] = b2f(av.z); As[alr][alc+3] = b2f(av.w);
        *(float4*)&Bs[blr][blc] = bv;
        __syncthreads();
#pragma unroll
        for (int k = 0; k < 16; k++) {
            float a[4], bb[4];
#pragma unroll
            for (int i = 0; i < 4; i++) a[i] = As[ty*4 + i][k];
#pragma unroll
            for (int j = 0; j < 4; j++) bb[j] = Bs[k][tx*4 + j];
#pragma unroll
            for (int i = 0; i < 4; i++)
#pragma unroll
                for (int j = 0; j < 4; j++) acc[i][j] += a[i] * bb[j];
        }
    }
#pragma unroll
    for (int i = 0; i < 4; i++) {
        float4 ov = make_float4(acc[i][0], acc[i][1], acc[i][2], acc[i][3]);
        *(float4*)(out + (size_t)(b * T_ + t0 + ty*4 + i) * D_ + d0 + tx*4) = ov;
    }
}

extern "C" void kernel_launch(void* const* d_in, const int* in_sizes, int n_in,
                              void* d_out, int out_size, void* d_ws, size_t ws_size,
                              hipStream_t stream)
{
    const float* x    = (const float*)d_in[0];
    const float* W    = (const float*)d_in[1];
    const float* bias = (const float*)d_in[2];
    float* outf = (float*)d_out;
    u16*   y    = (u16*)d_out;                          // first 32 MiB of d_out
    float* mptr = outf + (size_t)B_ * T_ * E_ / 2;      // after y (bf16 = half the floats)
    float* rptr = mptr + (size_t)B_ * T_;
    u16*   S    = (u16*)d_ws;                           // 64 MiB scores/P

    dim3 g1(E_ / 64, (B_ * T_) / 64);   // (16, 256)
    k1_proj<<<g1, 256, 0, stream>>>(x, W, bias, y);

    dim3 g2(T_ / 64, B_);               // (32, 8)
    k2_stats<<<g2, 256, 0, stream>>>(y, S, mptr, rptr);

    dim3 g3(B_ * T_);                   // 16384 rows
    k3_pnorm<<<g3, 256, 0, stream>>>(S, mptr, rptr);

    dim3 g4(D_ / 64, T_ / 64, B_);      // (16, 32, 8)
    k4_out<<<g4, 256, 0, stream>>>(S, x, outf);
}

// Round 2
// 587.493 us; speedup vs baseline: 5.9918x; 5.9918x over previous
//
#include <hip/hip_runtime.h>

// B=8, T=2048, D=1024, E=1024
//   y = bf16(x@W + b)                     -> d_out[0:33.5MB]
//   S[b,t,s] = bf16(y_t.y_s/32), s<=t     -> d_ws (64 MiB), lower-triangle tiles only
//   col stats: m_s=max_{t>=s} S, z_s=sumexp           (K2b)
//   P = exp(S-m_s)*r_s (in place, bf16)                (K3)
//   out[t,:] = sum_{s<=t} P[t,s]*x[s,:]   fp32         (K4, MFMA, causal k-range)
//
// MFMA 16x16x32 bf16 layouts (per guide, HW-verified):
//   A frag:  lane holds A[m=lane&15][k=(lane>>4)*8 + j], j=0..7  (short8)
//   B frag:  lane holds B[k=(lane>>4)*8 + j][n=lane&15]
//   C/D:     lane,reg r -> D[row=(lane>>4)*4+r][col=lane&15]
// Both A and B tiles are stored in LDS as [16-row][k-contiguous] so the frag
// load is a single 16B ds_read. LDS pitch 48 shorts (96 B): 16B-aligned rows,
// even bank coverage for b128 reads.

#define B_ 8
#define T_ 2048
#define D_ 1024
#define E_ 1024
#define PIT 48

typedef unsigned short u16;
typedef __attribute__((ext_vector_type(8))) short short8;
typedef __attribute__((ext_vector_type(4))) float floatx4;

__device__ __forceinline__ float b2f(u16 u) {
    unsigned v = ((unsigned)u) << 16;
    float f; __builtin_memcpy(&f, &v, 4); return f;
}
__device__ __forceinline__ u16 f2b(float f) {
    unsigned v; __builtin_memcpy(&v, &f, 4);
    v = (v + 0x7FFFu + ((v >> 16) & 1u)) >> 16;   // RNE
    return (u16)v;
}

// ---------------- K1: y = bf16(x @ W + b), MFMA ----------------
// M=16384, N=1024, K=1024. Block tile 128x128, BK=32.
__global__ __launch_bounds__(256) void k1_proj(const float* __restrict__ x,
                                               const float* __restrict__ W,
                                               const float* __restrict__ bias,
                                               u16* __restrict__ y)
{
    __shared__ u16 As[128 * PIT];
    __shared__ u16 Bs[128 * PIT];
    const int tid = threadIdx.x;
    const int lane = tid & 63, wid = tid >> 6;
    const int wr = (wid >> 1) * 64, wc = (wid & 1) * 64;
    const int l15 = lane & 15, q = lane >> 4;
    const int m0 = blockIdx.y * 128, n0 = blockIdx.x * 128;

    floatx4 acc[4][4];
#pragma unroll
    for (int i = 0; i < 4; i++)
#pragma unroll
        for (int j = 0; j < 4; j++) acc[i][j] = (floatx4){0.f, 0.f, 0.f, 0.f};

    for (int k0 = 0; k0 < D_; k0 += 32) {
        __syncthreads();
        // A: x[m0..+128][k0..+32] fp32 -> bf16, no transpose
#pragma unroll
        for (int u = 0; u < 4; u++) {
            const int c = tid * 4 + u;            // 1024 chunks
            const int row = c >> 3, c4 = c & 7;
            float4 v = *(const float4*)(x + (size_t)(m0 + row) * D_ + k0 + c4 * 4);
            u16* p = &As[row * PIT + c4 * 4];
            p[0] = f2b(v.x); p[1] = f2b(v.y); p[2] = f2b(v.z); p[3] = f2b(v.w);
        }
        // B: W[k0..+32][n0..+128] fp32 -> bf16, TRANSPOSED to Bs[n][k]
#pragma unroll
        for (int u = 0; u < 4; u++) {
            const int c = tid * 4 + u;
            const int kr = c >> 5, c4 = c & 31;
            float4 v = *(const float4*)(W + (size_t)(k0 + kr) * E_ + n0 + c4 * 4);
            Bs[(c4 * 4 + 0) * PIT + kr] = f2b(v.x);
            Bs[(c4 * 4 + 1) * PIT + kr] = f2b(v.y);
            Bs[(c4 * 4 + 2) * PIT + kr] = f2b(v.z);
            Bs[(c4 * 4 + 3) * PIT + kr] = f2b(v.w);
        }
        __syncthreads();
        short8 a[4], b[4];
#pragma unroll
        for (int i = 0; i < 4; i++) a[i] = *(const short8*)&As[(wr + i * 16 + l15) * PIT + q * 8];
#pragma unroll
        for (int j = 0; j < 4; j++) b[j] = *(const short8*)&Bs[(wc + j * 16 + l15) * PIT + q * 8];
#pragma unroll
        for (int i = 0; i < 4; i++)
#pragma unroll
            for (int j = 0; j < 4; j++)
                acc[i][j] = __builtin_amdgcn_mfma_f32_16x16x32_bf16(a[i], b[j], acc[i][j], 0, 0, 0);
    }
    float bv[4];
#pragma unroll
    for (int j = 0; j < 4; j++) bv[j] = bias[n0 + wc + j * 16 + l15];
#pragma unroll
    for (int i = 0; i < 4; i++)
#pragma unroll
        for (int j = 0; j < 4; j++)
#pragma unroll
            for (int r = 0; r < 4; r++) {
                const int gm = m0 + wr + i * 16 + q * 4 + r;
                const int gn = n0 + wc + j * 16 + l15;
                y[(size_t)gm * E_ + gn] = f2b(acc[i][j][r] + bv[j]);
            }
}

// ---------------- K2: S tiles = bf16(y_t . y_s / 32), lower triangle ----------------
__global__ __launch_bounds__(256) void k2_score(const u16* __restrict__ y,
                                                u16* __restrict__ S)
{
    __shared__ u16 As[128 * PIT];
    __shared__ u16 Bs[128 * PIT];
    const int tid = threadIdx.x;
    const int lane = tid & 63, wid = tid >> 6;
    const int wr = (wid >> 1) * 64, wc = (wid & 1) * 64;
    const int l15 = lane & 15, q = lane >> 4;
    // triangular decode: idx -> (it, js), js <= it
    int idx = blockIdx.x, it = 0, base = 0;
    while (base + it + 1 <= idx) { base += it + 1; it++; }
    const int js = idx - base;
    const int t0 = it * 128, s0 = js * 128;
    const int b = blockIdx.y;
    const u16* yb = y + (size_t)b * T_ * E_;

    floatx4 acc[4][4];
#pragma unroll
    for (int i = 0; i < 4; i++)
#pragma unroll
        for (int j = 0; j < 4; j++) acc[i][j] = (floatx4){0.f, 0.f, 0.f, 0.f};

    for (int k0 = 0; k0 < E_; k0 += 32) {
        __syncthreads();
#pragma unroll
        for (int u = 0; u < 2; u++) {            // A tile: y rows t0.. (bf16, 16B chunks)
            const int c = tid * 2 + u;           // 512 chunks
            const int row = c >> 2, off = c & 3;
            *(uint4*)&As[row * PIT + off * 8] =
                *(const uint4*)(yb + (size_t)(t0 + row) * E_ + k0 + off * 8);
        }
#pragma unroll
        for (int u = 0; u < 2; u++) {            // B tile: y rows s0..
            const int c = tid * 2 + u;
            const int row = c >> 2, off = c & 3;
            *(uint4*)&Bs[row * PIT + off * 8] =
                *(const uint4*)(yb + (size_t)(s0 + row) * E_ + k0 + off * 8);
        }
        __syncthreads();
        short8 a[4], b2[4];
#pragma unroll
        for (int i = 0; i < 4; i++) a[i] = *(const short8*)&As[(wr + i * 16 + l15) * PIT + q * 8];
#pragma unroll
        for (int j = 0; j < 4; j++) b2[j] = *(const short8*)&Bs[(wc + j * 16 + l15) * PIT + q * 8];
#pragma unroll
        for (int i = 0; i < 4; i++)
#pragma unroll
            for (int j = 0; j < 4; j++)
                acc[i][j] = __builtin_amdgcn_mfma_f32_16x16x32_bf16(a[i], b2[j], acc[i][j], 0, 0, 0);
    }
#pragma unroll
    for (int i = 0; i < 4; i++)
#pragma unroll
        for (int j = 0; j < 4; j++)
#pragma unroll
            for (int r = 0; r < 4; r++) {
                const int t = t0 + wr + i * 16 + q * 4 + r;
                const int s = s0 + wc + j * 16 + l15;
                u16 o = (t < s) ? (u16)0xFF7F : f2b(acc[i][j][r] * 0.03125f);
                S[((size_t)(b * T_ + t)) * T_ + s] = o;
            }
}

// ---------------- K2b: per-column (m, 1/z) over t >= s ----------------
// Block: 64 columns of one batch; LDS-tiled 64x64 chunks down the column.
__global__ __launch_bounds__(256) void k2b_stats(const u16* __restrict__ S,
                                                 float* __restrict__ mout,
                                                 float* __restrict__ rout)
{
    __shared__ u16 St[64 * 64];
    __shared__ float sm[4][64], sz[4][64];
    const int tid = threadIdx.x;
    const int lane = tid & 63, w = tid >> 6;
    const int b = blockIdx.y;
    const int s0 = blockIdx.x * 64;
    const u16* Sb = S + (size_t)b * T_ * T_;
    float m = -3e38f, z = 0.f;
    for (int t0 = s0; t0 < T_; t0 += 64) {
        __syncthreads();
#pragma unroll
        for (int u = 0; u < 2; u++) {
            const int c = tid * 2 + u;           // 512 16B chunks
            const int row = c >> 3, off = c & 7;
            *(uint4*)&St[row * 64 + off * 8] =
                *(const uint4*)(Sb + (size_t)(t0 + row) * T_ + s0 + off * 8);
        }
        __syncthreads();
#pragma unroll
        for (int i = 0; i < 16; i++) {
            const float v = b2f(St[(w * 16 + i) * 64 + lane]);
            if (v > m) { z = z * __expf(m - v) + 1.f; m = v; }
            else z += __expf(v - m);
        }
    }
    sm[w][lane] = m; sz[w][lane] = z;
    __syncthreads();
    if (tid < 64) {
        float mm = sm[0][tid];
#pragma unroll
        for (int rr = 1; rr < 4; rr++) mm = fmaxf(mm, sm[rr][tid]);
        float zz = 0.f;
#pragma unroll
        for (int rr = 0; rr < 4; rr++) zz += sz[rr][tid] * __expf(sm[rr][tid] - mm);
        mout[(size_t)b * T_ + s0 + tid] = mm;
        rout[(size_t)b * T_ + s0 + tid] = 1.0f / zz;
    }
}

// ---------------- K3: P = exp(S - m_s) * r_s  (in place, bf16) ----------------
__global__ __launch_bounds__(256) void k3_pnorm(u16* __restrict__ S,
                                                const float* __restrict__ m,
                                                const float* __restrict__ r)
{
    const int row = blockIdx.x;          // b*T + t
    const int b = row >> 11;
    const int t = row & (T_ - 1);
    const int s0 = threadIdx.x * 8;
    u16* Sp = S + (size_t)row * T_ + s0;
    const float* mb = m + (size_t)b * T_;
    const float* rb = r + (size_t)b * T_;
    ushort4 v0 = *(ushort4*)Sp;
    ushort4 v1 = *(ushort4*)(Sp + 4);
    u16 vv[8] = { v0.x, v0.y, v0.z, v0.w, v1.x, v1.y, v1.z, v1.w };
    u16 ov[8];
#pragma unroll
    for (int i = 0; i < 8; i++) {
        const int s = s0 + i;
        float p = 0.f;
        if (s <= t) p = __expf(b2f(vv[i]) - mb[s]) * rb[s];
        ov[i] = f2b(p);
    }
    *(ushort4*)Sp       = make_ushort4(ov[0], ov[1], ov[2], ov[3]);
    *(ushort4*)(Sp + 4) = make_ushort4(ov[4], ov[5], ov[6], ov[7]);
}

// ---------------- K4: out = P @ x  (MFMA, causal k-range, fp32 out) ----------------
__global__ __launch_bounds__(256) void k4_out(const u16* __restrict__ P,
                                              const float* __restrict__ x,
                                              float* __restrict__ out)
{
    __shared__ u16 As[128 * PIT];
    __shared__ u16 Bs[128 * PIT];
    const int tid = threadIdx.x;
    const int lane = tid & 63, wid = tid >> 6;
    const int wr = (wid >> 1) * 64, wc = (wid & 1) * 64;
    const int l15 = lane & 15, q = lane >> 4;
    const int it = (T_ / 128 - 1) - blockIdx.y;   // heavy tiles dispatched first
    const int t0 = it * 128;
    const int d0 = blockIdx.x * 128;
    const int b = blockIdx.z;
    const u16* Pb = P + (size_t)b * T_ * T_;
    const float* xb = x + (size_t)b * T_ * D_;

    floatx4 acc[4][4];
#pragma unroll
    for (int i = 0; i < 4; i++)
#pragma unroll
        for (int j = 0; j < 4; j++) acc[i][j] = (floatx4){0.f, 0.f, 0.f, 0.f};

    const int kend = t0 + 128;                    // P[t][s]=0 for s>t
    for (int k0 = 0; k0 < kend; k0 += 32) {
        __syncthreads();
#pragma unroll
        for (int u = 0; u < 2; u++) {             // A: P rows t0.. (bf16, stride T_)
            const int c = tid * 2 + u;
            const int row = c >> 2, off = c & 3;
            *(uint4*)&As[row * PIT + off * 8] =
                *(const uint4*)(Pb + (size_t)(t0 + row) * T_ + k0 + off * 8);
        }
#pragma unroll
        for (int u = 0; u < 4; u++) {             // B: x[k0..+32][d0..+128] fp32, transposed
            const int c = tid * 4 + u;
            const int kr = c >> 5, c4 = c & 31;
            float4 v = *(const float4*)(xb + (size_t)(k0 + kr) * D_ + d0 + c4 * 4);
            Bs[(c4 * 4 + 0) * PIT + kr] = f2b(v.x);
            Bs[(c4 * 4 + 1) * PIT + kr] = f2b(v.y);
            Bs[(c4 * 4 + 2) * PIT + kr] = f2b(v.z);
            Bs[(c4 * 4 + 3) * PIT + kr] = f2b(v.w);
        }
        __syncthreads();
        short8 a[4], b2[4];
#pragma unroll
        for (int i = 0; i < 4; i++) a[i] = *(const short8*)&As[(wr + i * 16 + l15) * PIT + q * 8];
#pragma unroll
        for (int j = 0; j < 4; j++) b2[j] = *(const short8*)&Bs[(wc + j * 16 + l15) * PIT + q * 8];
#pragma unroll
        for (int i = 0; i < 4; i++)
#pragma unroll
            for (int j = 0; j < 4; j++)
                acc[i][j] = __builtin_amdgcn_mfma_f32_16x16x32_bf16(a[i], b2[j], acc[i][j], 0, 0, 0);
    }
#pragma unroll
    for (int i = 0; i < 4; i++)
#pragma unroll
        for (int j = 0; j < 4; j++)
#pragma unroll
            for (int r = 0; r < 4; r++) {
                const int gt = t0 + wr + i * 16 + q * 4 + r;
                const int gd = d0 + wc + j * 16 + l15;
                out[(size_t)(b * T_ + gt) * D_ + gd] = acc[i][j][r];
            }
}

extern "C" void kernel_launch(void* const* d_in, const int* in_sizes, int n_in,
                              void* d_out, int out_size, void* d_ws, size_t ws_size,
                              hipStream_t stream)
{
    const float* x    = (const float*)d_in[0];
    const float* W    = (const float*)d_in[1];
    const float* bias = (const float*)d_in[2];
    float* outf = (float*)d_out;
    u16*   y    = (u16*)d_out;                      // 33.5 MB
    float* mptr = outf + (size_t)B_ * T_ * E_ / 2;  // after y
    float* rptr = mptr + (size_t)B_ * T_;
    u16*   S    = (u16*)d_ws;                       // 64 MiB

    dim3 g1(E_ / 128, (B_ * T_) / 128);   // (8, 128)
    k1_proj<<<g1, 256, 0, stream>>>(x, W, bias, y);

    dim3 g2(136, B_);                     // lower-triangle tile pairs
    k2_score<<<g2, 256, 0, stream>>>(y, S);

    dim3 g2b(T_ / 64, B_);                // (32, 8)
    k2b_stats<<<g2b, 256, 0, stream>>>(S, mptr, rptr);

    dim3 g3(B_ * T_);
    k3_pnorm<<<g3, 256, 0, stream>>>(S, mptr, rptr);

    dim3 g4(D_ / 128, T_ / 128, B_);      // (8, 16, 8)
    k4_out<<<g4, 256, 0, stream>>>(S, x, outf);
}

// Round 4
// 456.219 us; speedup vs baseline: 7.7158x; 1.2877x over previous
//
#include <hip/hip_runtime.h>

// B=8, T=2048, D=1024, E=1024
//   k0: WT = bf16(W^T)                  -> d_out[32MiB..34MiB] (dead before k4)
//   k1: y = bf16(x@W + b)               -> d_out[0:32MiB]   (MFMA, B from WT)
//   k2: S[b,t,s] = bf16(y_t.y_s/32)     -> d_ws, lower-triangle tiles
//   k2b: col stats m_s,r_s=1/z_s        -> stashed in S's dead zone (upper tiles)
//   k3: P = exp(S-m_s)*r_s in place     (causal-restricted)
//   k4: out = P @ x  fp32               (MFMA, B = column-gathered x)
//
// MFMA 16x16x32 bf16 frag layouts (HW-verified):
//   A: lane holds A[m=lane&15][k=q*8+j]; B: B[k=q*8+j][n=lane&15]
//   C/D: lane,reg r -> D[row=q*4+r][col=lane&15]
// LDS pitch 56 shorts (112 B = 7*16): rows 16B-aligned; 28 dwords/row means
// row-strided b128 accesses and l15-strided frag reads both cover all 32
// banks at <=2 lanes/bank (free per m136).

#define B_ 8
#define T_ 2048
#define D_ 1024
#define E_ 1024
#define PIT 56

typedef unsigned short u16;
typedef __attribute__((ext_vector_type(8))) short short8;
typedef __attribute__((ext_vector_type(4))) float floatx4;

__device__ __forceinline__ float b2f(u16 u) {
    unsigned v = ((unsigned)u) << 16;
    float f; __builtin_memcpy(&f, &v, 4); return f;
}
__device__ __forceinline__ u16 f2b(float f) {
    unsigned v; __builtin_memcpy(&v, &f, 4);
    v = (v + 0x7FFFu + ((v >> 16) & 1u)) >> 16;   // RNE
    return (u16)v;
}

// m/r stash inside S's strictly-upper dead zone (batch 0, rows 0..63, cols 1024+):
// never read/written by k2 (lower tiles), k2b (t>=s0 walk), k3 (s<sEnd<=ceil128(t+1)),
// k4 (cols < t0+128 for rows t0..). which: 0=m, 1=r.
__device__ __forceinline__ float* mr_ptr(u16* S, int which, int b, int s) {
    const int row = which * 32 + b * 4 + (s >> 9);
    return (float*)(S + (size_t)row * T_ + 1024 + (s & 511) * 2);
}

// ---------------- K0: WT[n][k] = bf16(W[k][n]) ----------------
__global__ __launch_bounds__(256) void k0_wt(const float* __restrict__ W,
                                             u16* __restrict__ WT)
{
    __shared__ float Ws[64 * 68];          // pitch 68 floats = 272 B (16B-aligned)
    const int tid = threadIdx.x;
    const int k0 = blockIdx.x * 64, n0 = blockIdx.y * 64;
#pragma unroll
    for (int u = 0; u < 4; u++) {
        const int c = tid + 256 * u;       // 1024 float4 chunks
        const int row = c >> 4, c4 = c & 15;
        float4 v = *(const float4*)(W + (size_t)(k0 + row) * E_ + n0 + c4 * 4);
        *(float4*)&Ws[row * 68 + c4 * 4] = v;
    }
    __syncthreads();
#pragma unroll
    for (int u = 0; u < 2; u++) {
        const int c = tid + 256 * u;       // 512 short8 chunks
        const int n = c >> 3, kc = c & 7;
        short8 pk;
#pragma unroll
        for (int j = 0; j < 8; j++) pk[j] = (short)f2b(Ws[(kc * 8 + j) * 68 + n]);
        *(short8*)(WT + (size_t)(n0 + n) * D_ + k0 + kc * 8) = pk;
    }
}

// ---------------- K1: y = bf16(x @ W + b), MFMA ----------------
__global__ __launch_bounds__(256) void k1_proj(const float* __restrict__ x,
                                               const u16* __restrict__ WT,
                                               const float* __restrict__ bias,
                                               u16* __restrict__ y)
{
    __shared__ u16 As[128 * PIT];
    __shared__ u16 Bs[128 * PIT];
    const int tid = threadIdx.x;
    const int lane = tid & 63, wid = tid >> 6;
    const int wr = (wid >> 1) * 64, wc = (wid & 1) * 64;
    const int l15 = lane & 15, q = lane >> 4;
    const int m0 = blockIdx.y * 128, n0 = blockIdx.x * 128;

    floatx4 acc[4][4];
#pragma unroll
    for (int i = 0; i < 4; i++)
#pragma unroll
        for (int j = 0; j < 4; j++) acc[i][j] = (floatx4){0.f, 0.f, 0.f, 0.f};

    for (int k0 = 0; k0 < D_; k0 += 32) {
        __syncthreads();
        // A: x[m0..+128][k0..+32] fp32 -> bf16, row-major (no transpose)
#pragma unroll
        for (int u = 0; u < 4; u++) {
            const int c = tid * 4 + u;            // 1024 float4 chunks
            const int row = c >> 3, c4 = c & 7;
            float4 v = *(const float4*)(x + (size_t)(m0 + row) * D_ + k0 + c4 * 4);
            ushort4 pk = make_ushort4(f2b(v.x), f2b(v.y), f2b(v.z), f2b(v.w));
            *(ushort4*)&As[row * PIT + c4 * 4] = pk;     // 8B-aligned
        }
        // B: WT rows (already [n][k] bf16) — pure 16B copies
#pragma unroll
        for (int u = 0; u < 2; u++) {
            const int c = tid * 2 + u;            // 512 chunks
            const int row = c >> 2, off = c & 3;
            *(uint4*)&Bs[row * PIT + off * 8] =
                *(const uint4*)(WT + (size_t)(n0 + row) * D_ + k0 + off * 8);
        }
        __syncthreads();
        short8 a[4], b2[4];
#pragma unroll
        for (int i = 0; i < 4; i++) a[i] = *(const short8*)&As[(wr + i * 16 + l15) * PIT + q * 8];
#pragma unroll
        for (int j = 0; j < 4; j++) b2[j] = *(const short8*)&Bs[(wc + j * 16 + l15) * PIT + q * 8];
#pragma unroll
        for (int i = 0; i < 4; i++)
#pragma unroll
            for (int j = 0; j < 4; j++)
                acc[i][j] = __builtin_amdgcn_mfma_f32_16x16x32_bf16(a[i], b2[j], acc[i][j], 0, 0, 0);
    }
    float bv[4];
#pragma unroll
    for (int j = 0; j < 4; j++) bv[j] = bias[n0 + wc + j * 16 + l15];
#pragma unroll
    for (int i = 0; i < 4; i++)
#pragma unroll
        for (int j = 0; j < 4; j++)
#pragma unroll
            for (int r = 0; r < 4; r++) {
                const int gm = m0 + wr + i * 16 + q * 4 + r;
                const int gn = n0 + wc + j * 16 + l15;
                y[(size_t)gm * E_ + gn] = f2b(acc[i][j][r] + bv[j]);
            }
}

// ---------------- K2: S tiles = bf16(y_t . y_s / 32), lower triangle ----------------
__global__ __launch_bounds__(256) void k2_score(const u16* __restrict__ y,
                                                u16* __restrict__ S)
{
    __shared__ u16 As[128 * PIT];
    __shared__ u16 Bs[128 * PIT];
    const int tid = threadIdx.x;
    const int lane = tid & 63, wid = tid >> 6;
    const int wr = (wid >> 1) * 64, wc = (wid & 1) * 64;
    const int l15 = lane & 15, q = lane >> 4;
    int idx = blockIdx.x, it = 0, base = 0;
    while (base + it + 1 <= idx) { base += it + 1; it++; }
    const int js = idx - base;
    const int t0 = it * 128, s0 = js * 128;
    const int b = blockIdx.y;
    const u16* yb = y + (size_t)b * T_ * E_;

    floatx4 acc[4][4];
#pragma unroll
    for (int i = 0; i < 4; i++)
#pragma unroll
        for (int j = 0; j < 4; j++) acc[i][j] = (floatx4){0.f, 0.f, 0.f, 0.f};

    for (int k0 = 0; k0 < E_; k0 += 32) {
        __syncthreads();
#pragma unroll
        for (int u = 0; u < 2; u++) {
            const int c = tid * 2 + u;
            const int row = c >> 2, off = c & 3;
            *(uint4*)&As[row * PIT + off * 8] =
                *(const uint4*)(yb + (size_t)(t0 + row) * E_ + k0 + off * 8);
        }
#pragma unroll
        for (int u = 0; u < 2; u++) {
            const int c = tid * 2 + u;
            const int row = c >> 2, off = c & 3;
            *(uint4*)&Bs[row * PIT + off * 8] =
                *(const uint4*)(yb + (size_t)(s0 + row) * E_ + k0 + off * 8);
        }
        __syncthreads();
        short8 a[4], b2[4];
#pragma unroll
        for (int i = 0; i < 4; i++) a[i] = *(const short8*)&As[(wr + i * 16 + l15) * PIT + q * 8];
#pragma unroll
        for (int j = 0; j < 4; j++) b2[j] = *(const short8*)&Bs[(wc + j * 16 + l15) * PIT + q * 8];
#pragma unroll
        for (int i = 0; i < 4; i++)
#pragma unroll
            for (int j = 0; j < 4; j++)
                acc[i][j] = __builtin_amdgcn_mfma_f32_16x16x32_bf16(a[i], b2[j], acc[i][j], 0, 0, 0);
    }
#pragma unroll
    for (int i = 0; i < 4; i++)
#pragma unroll
        for (int j = 0; j < 4; j++)
#pragma unroll
            for (int r = 0; r < 4; r++) {
                const int t = t0 + wr + i * 16 + q * 4 + r;
                const int s = s0 + wc + j * 16 + l15;
                u16 o = (t < s) ? (u16)0xFF7F : f2b(acc[i][j][r] * 0.03125f);
                S[((size_t)(b * T_ + t)) * T_ + s] = o;
            }
}

// ---------------- K2b: per-column (m, 1/z) over t >= s ----------------
__global__ __launch_bounds__(256) void k2b_stats(u16* __restrict__ S)
{
    __shared__ u16 St[64 * 64];
    __shared__ float sm[4][64], sz[4][64];
    const int tid = threadIdx.x;
    const int lane = tid & 63, w = tid >> 6;
    const int b = blockIdx.y;
    const int s0 = blockIdx.x * 64;
    const u16* Sb = S + (size_t)b * T_ * T_;
    float m = -3e38f, z = 0.f;
    for (int t0 = s0; t0 < T_; t0 += 64) {
        __syncthreads();
#pragma unroll
        for (int u = 0; u < 2; u++) {
            const int c = tid * 2 + u;
            const int row = c >> 3, off = c & 7;
            *(uint4*)&St[row * 64 + off * 8] =
                *(const uint4*)(Sb + (size_t)(t0 + row) * T_ + s0 + off * 8);
        }
        __syncthreads();
#pragma unroll
        for (int i = 0; i < 16; i++) {
            const float v = b2f(St[(w * 16 + i) * 64 + lane]);
            if (v > m) { z = z * __expf(m - v) + 1.f; m = v; }
            else z += __expf(v - m);
        }
    }
    sm[w][lane] = m; sz[w][lane] = z;
    __syncthreads();
    if (tid < 64) {
        float mm = sm[0][tid];
#pragma unroll
        for (int rr = 1; rr < 4; rr++) mm = fmaxf(mm, sm[rr][tid]);
        float zz = 0.f;
#pragma unroll
        for (int rr = 0; rr < 4; rr++) zz += sz[rr][tid] * __expf(sm[rr][tid] - mm);
        *mr_ptr(S, 0, b, s0 + tid) = mm;
        *mr_ptr(S, 1, b, s0 + tid) = 1.0f / zz;
    }
}

// ---------------- K3: P = exp(S - m_s) * r_s  (in place, causal-restricted) ----------------
__global__ __launch_bounds__(256) void k3_pnorm(u16* __restrict__ S)
{
    const int row = blockIdx.x;          // b*T + t
    const int b = row >> 11;
    const int t = row & (T_ - 1);
    const int sEnd = ((t >> 7) + 1) << 7;    // tile-ceil(t+1)
    const int s0 = threadIdx.x * 8;
    if (s0 >= sEnd) return;
    u16* Sp = S + (size_t)row * T_ + s0;
    const float* mp = mr_ptr(S, 0, b, s0);
    const float* rp = mr_ptr(S, 1, b, s0);
    float mv[8], rv[8];
    *(float4*)&mv[0] = *(const float4*)mp;
    *(float4*)&mv[4] = *((const float4*)mp + 1);
    *(float4*)&rv[0] = *(const float4*)rp;
    *(float4*)&rv[4] = *((const float4*)rp + 1);
    ushort4 v0 = *(ushort4*)Sp;
    ushort4 v1 = *(ushort4*)(Sp + 4);
    u16 vv[8] = { v0.x, v0.y, v0.z, v0.w, v1.x, v1.y, v1.z, v1.w };
    u16 ov[8];
#pragma unroll
    for (int i = 0; i < 8; i++) {
        const int s = s0 + i;
        float p = 0.f;
        if (s <= t) p = __expf(b2f(vv[i]) - mv[i]) * rv[i];
        ov[i] = f2b(p);
    }
    *(ushort4*)Sp       = make_ushort4(ov[0], ov[1], ov[2], ov[3]);
    *(ushort4*)(Sp + 4) = make_ushort4(ov[4], ov[5], ov[6], ov[7]);
}

// ---------------- K4: out = P @ x  (MFMA, B = column-gathered x) ----------------
__global__ __launch_bounds__(256) void k4_out(const u16* __restrict__ P,
                                              const float* __restrict__ x,
                                              float* __restrict__ out)
{
    __shared__ u16 As[128 * PIT];
    __shared__ u16 Bs[128 * PIT];
    const int tid = threadIdx.x;
    const int lane = tid & 63, wid = tid >> 6;
    const int wr = (wid >> 1) * 64, wc = (wid & 1) * 64;
    const int l15 = lane & 15, q = lane >> 4;
    const int it = (T_ / 128 - 1) - blockIdx.y;   // heavy tiles first
    const int t0 = it * 128;
    const int d0 = blockIdx.x * 128;
    const int b = blockIdx.z;
    const u16* Pb = P + (size_t)b * T_ * T_;
    const float* xb = x + (size_t)b * T_ * D_;
    const int gn = tid & 127;           // gather column
    const int kh0 = (tid >> 7) * 2;     // 0 or 2

    floatx4 acc[4][4];
#pragma unroll
    for (int i = 0; i < 4; i++)
#pragma unroll
        for (int j = 0; j < 4; j++) acc[i][j] = (floatx4){0.f, 0.f, 0.f, 0.f};

    const int kend = t0 + 128;
    for (int k0 = 0; k0 < kend; k0 += 32) {
        __syncthreads();
        // A: P rows, pure 16B copies
#pragma unroll
        for (int u = 0; u < 2; u++) {
            const int c = tid * 2 + u;
            const int row = c >> 2, off = c & 3;
            *(uint4*)&As[row * PIT + off * 8] =
                *(const uint4*)(Pb + (size_t)(t0 + row) * T_ + k0 + off * 8);
        }
        // B: gather x columns -> bf16 short8 -> single b128 store (PIT=56: conflict-free)
#pragma unroll
        for (int u = 0; u < 2; u++) {
            const int kh = kh0 + u;
            float f[8];
#pragma unroll
            for (int j = 0; j < 8; j++)
                f[j] = xb[(size_t)(k0 + kh * 8 + j) * D_ + d0 + gn];
            short8 pk;
#pragma unroll
            for (int j = 0; j < 8; j++) pk[j] = (short)f2b(f[j]);
            *(short8*)&Bs[gn * PIT + kh * 8] = pk;
        }
        __syncthreads();
        short8 a[4], b2[4];
#pragma unroll
        for (int i = 0; i < 4; i++) a[i] = *(const short8*)&As[(wr + i * 16 + l15) * PIT + q * 8];
#pragma unroll
        for (int j = 0; j < 4; j++) b2[j] = *(const short8*)&Bs[(wc + j * 16 + l15) * PIT + q * 8];
#pragma unroll
        for (int i = 0; i < 4; i++)
#pragma unroll
            for (int j = 0; j < 4; j++)
                acc[i][j] = __builtin_amdgcn_mfma_f32_16x16x32_bf16(a[i], b2[j], acc[i][j], 0, 0, 0);
    }
#pragma unroll
    for (int i = 0; i < 4; i++)
#pragma unroll
        for (int j = 0; j < 4; j++)
#pragma unroll
            for (int r = 0; r < 4; r++) {
                const int gt = t0 + wr + i * 16 + q * 4 + r;
                const int gd = d0 + wc + j * 16 + l15;
                out[(size_t)(b * T_ + gt) * D_ + gd] = acc[i][j][r];
            }
}

extern "C" void kernel_launch(void* const* d_in, const int* in_sizes, int n_in,
                              void* d_out, int out_size, void* d_ws, size_t ws_size,
                              hipStream_t stream)
{
    const float* x    = (const float*)d_in[0];
    const float* W    = (const float*)d_in[1];
    const float* bias = (const float*)d_in[2];
    float* outf = (float*)d_out;
    u16*   y    = (u16*)d_out;                  // bf16, first 32 MiB of d_out
    u16*   WT   = y + ((size_t)1 << 24);        // 32MiB..34MiB of d_out (dead before k4)
    u16*   S    = (u16*)d_ws;                   // 64 MiB (m/r stashed in dead zone)

    dim3 g0(D_ / 64, E_ / 64);            // (16,16)
    k0_wt<<<g0, 256, 0, stream>>>(W, WT);

    dim3 g1(E_ / 128, (B_ * T_) / 128);   // (8, 128)
    k1_proj<<<g1, 256, 0, stream>>>(x, WT, bias, y);

    dim3 g2(136, B_);
    k2_score<<<g2, 256, 0, stream>>>(y, S);

    dim3 g2b(T_ / 64, B_);                // (32, 8)
    k2b_stats<<<g2b, 256, 0, stream>>>(S);

    dim3 g3(B_ * T_);
    k3_pnorm<<<g3, 256, 0, stream>>>(S);

    dim3 g4(D_ / 128, T_ / 128, B_);      // (8, 16, 8)
    k4_out<<<g4, 256, 0, stream>>>(S, x, outf);
}